// Round 17
// baseline (213.274 us; speedup 1.0000x reference)
//
#include <hip/hip_runtime.h>
#include <math.h>

#define BS 4
#define NCH 20
#define IMH 480
#define IMW 640
#define NPIX (IMH*IMW)           /* 307200 */
#define MSZ 480
#define MPX (MSZ*MSZ)            /* 230400 */
#define VR 100

#define TX 5
#define TY 4
#define NRX 20
#define NRY 25
#define NBIN (NRX*NRY)           /* 500 */
#define NBINT (BS*NBIN)          /* 2000 */
#define CELLS (TX*TY)            /* 20 */
#define C0STRIDE 49              /* u32 stride, odd -> bank spread */
#define SEMSTRIDE 177            /* u64 stride, mod 16 == 1 -> bank-pair spread (22*8=176 used) */
/* LDS: 20*49*4 + 20*177*8 = 3920 + 28320 = 32240 B -> 4 blocks/CU at 512 thr (32 waves = full) */

#define WND 176                  /* heavy-pass window (>= 152 worst-case) */
#define NT  11                   /* WND/16 */

#define FPSCALE 65536.0f
#define FPINV   (1.0f/65536.0f)
#define SEMSCALE 65535.0f
#define SEMINV   (1.0f/65535.0f)

#define FCONST 388.19028f        /* 320 / tan(39.5 deg) */
#define D2R    0.017453292519943295f
#define R2DF   57.29577951308232f

typedef float    fx4  __attribute__((ext_vector_type(4)));
typedef unsigned ux4  __attribute__((ext_vector_type(4)));

static constexpr size_t SEG = (size_t)BS*NCH*MPX;            // 18,432,000 floats per output map
static constexpr size_t SEMT_FLOATS = (size_t)BS*NPIX*8;     // u16 semT = 9,830,400 float-equivalents
static constexpr size_t LIST_CAP    = (size_t)4*BS*NPIX;     // 4,915,200 entries (max 4 bins/pixel)
// out-segment fallback layout:
static constexpr size_t LIST_OFF_OUT = SEMT_FLOATS;
static_assert(LIST_OFF_OUT + LIST_CAP < 2*SEG, "semT+list must fit in out0+out1 segments");

// ws layout (float offsets) — counts/curs CONTIGUOUS (k_zero zeroes both in one pass)
static constexpr size_t OFF_AV     = 0;                        // BS*18*10000
static constexpr size_t OFF_AVS    = 720000;                   // BS*10000
static constexpr size_t OFF_COUNTS = 1681664;                  // NBINT uints
static constexpr size_t OFF_CURS   = OFF_COUNTS + NBINT;       // 1683664 (contiguous with counts!)
static constexpr size_t OFF_OFFS   = OFF_CURS + NBINT;         // 1685664
static constexpr size_t OFF_SEMT   = 1687664;                  // %4==0 -> 16B aligned
static constexpr size_t OFF_LIST   = OFF_SEMT + SEMT_FLOATS;   // 11,518,064
static constexpr size_t WS_NEED_B  = (OFF_LIST + LIST_CAP) * 4;  // ~65.7 MB
static_assert(OFF_SEMT % 4 == 0, "semT must be 16B aligned");

__device__ __forceinline__ float clip01(float v) { return fminf(fmaxf(v, 0.0f), 1.0f); }

struct Geo { float px, py, pz; };

__device__ __forceinline__ Geo geom(int p, float depth, float ca, float sa) {
  int j = p % IMW;
  int i = p / IMW;
  float dF = depth * (1.0f / FCONST);
  float X  = ((float)j - 319.5f) * dF;
  X += 250.0f;
  float gz = (float)(IMH - 1 - i);
  float Zc = (gz - 239.5f) * dF;
  float Y  = ca*depth - sa*Zc;
  float Z  = sa*depth + ca*Zc + 88.0f;
  float xs = (X/5.0f - 50.0f)/100.0f*2.0f;
  float ys = (Y/5.0f - 50.0f)/100.0f*2.0f;
  float zs = (Z/5.0f - 16.0f)/48.0f*2.0f;
  Geo g;
  g.px = xs*50.0f + 50.0f;
  g.py = ys*50.0f + 50.0f;
  g.pz = zs*24.0f + 24.0f;
  return g;
}

__device__ __forceinline__ int pixel_bins(Geo g, int bins[4]) {
  float fx = floorf(g.px), fy = floorf(g.py), fz = floorf(g.pz);
  float fx1 = fx + 1.0f, fy1 = fy + 1.0f, fz1 = fz + 1.0f;
  bool vx0 = (fx  > 0.0f) && (fx  < 100.0f);
  bool vx1 = (fx1 > 0.0f) && (fx1 < 100.0f);
  bool vy0 = (fy  > 0.0f) && (fy  < 100.0f);
  bool vy1 = (fy1 > 0.0f) && (fy1 < 100.0f);
  bool vz0 = (fz  > 0.0f) && (fz  < 48.0f);
  bool vz1 = (fz1 > 0.0f) && (fz1 < 48.0f);
  if (!((vx0||vx1) && (vy0||vy1) && (vz0||vz1))) return 0;
  int rxs[2]; int nx = 0;
  if (vx0) rxs[nx++] = (int)fx / TX;
  if (vx1) { int r = (int)fx1 / TX; if (!nx || r != rxs[0]) rxs[nx++] = r; }
  int rys[2]; int ny = 0;
  if (vy0) rys[ny++] = (int)fy / TY;
  if (vy1) { int r = (int)fy1 / TY; if (!ny || r != rys[0]) rys[ny++] = r; }
  int n = 0;
  for (int a = 0; a < ny; ++a)
    for (int c = 0; c < nx; ++c)
      bins[n++] = rys[a]*NRX + rxs[c];
  return n;
}

__device__ __forceinline__ void pose_calc(const float* __restrict__ pose_obs,
                                          const float* __restrict__ poses_last,
                                          int b, float& nx, float& ny, float& nt) {
  float pl0 = poses_last[b*3+0], pl1 = poses_last[b*3+1], pl2 = poses_last[b*3+2];
  float po0 = pose_obs[b*3+0],   po1 = pose_obs[b*3+1],   po2 = pose_obs[b*3+2];
  float r  = pl2 / R2DF;
  float sr = sinf(r), cr = cosf(r);
  ny = pl1 + po0*sr + po1*cr;
  nx = pl0 + po0*cr - po1*sr;
  nt = pl2 + po2*R2DF;
  nt = fmodf(nt - 180.0f, 360.0f) + 180.0f;
  nt = fmodf(nt + 180.0f, 360.0f) - 180.0f;
}

// ---------------------------------------------------------------- zero counts+curs (contiguous 2*NBINT words)
__global__ __launch_bounds__(256) void k_zero(unsigned* __restrict__ counts_curs) {
  int i = blockIdx.x * 256 + threadIdx.x;
  if (i < 2*NBINT) counts_curs[i] = 0u;
}

// ---------------------------------------------------------------- prep: bin count + predicated u16 sem transpose (+ poses output)
__global__ __launch_bounds__(256) void k_prep(const float* __restrict__ obs,
                                              const float* __restrict__ pose_obs,
                                              const float* __restrict__ poses_last,
                                              const float* __restrict__ eve,
                                              unsigned* __restrict__ counts,
                                              unsigned short* __restrict__ semT,
                                              float* __restrict__ out_poses) {
  __shared__ unsigned hist[NBIN];
  int tid = threadIdx.x;
  int b   = blockIdx.y;
  if (blockIdx.x == 0 && b == 0 && tid < BS) {
    float nx, ny, nt;
    pose_calc(pose_obs, poses_last, tid, nx, ny, nt);
    out_poses[tid*3+0] = nx;
    out_poses[tid*3+1] = ny;
    out_poses[tid*3+2] = nt;
  }
  for (int i = tid; i < NBIN; i += 256) hist[i] = 0u;
  __syncthreads();
  float a  = eve[b] * D2R;
  float ca = cosf(a), sa = sinf(a);
  const float* __restrict__ dpl  = obs + ((size_t)b*NCH + 3)*NPIX;
  const float* __restrict__ semb = obs + ((size_t)b*NCH + 4)*NPIX;
  int base = blockIdx.x * 2048;
#pragma unroll
  for (int k = 0; k < 8; ++k) {
    int p = base + k*256 + tid;
    Geo g = geom(p, dpl[p], ca, sa);
    int bins[4];
    int n = pixel_bins(g, bins);
    for (int t = 0; t < n; ++t) atomicAdd(&hist[bins[t]], 1u);
    bool wantSem = false;
    if (n > 0) {
      float fz = floorf(g.pz);
#pragma unroll
      for (int kk = 0; kk < 2; ++kk) {
        float pv = fz + (float)kk;
        if (pv > 0.0f && pv < 48.0f) {
          int zv = (int)pv;
          if (zv >= 13 && zv < 35) wantSem = true;
        }
      }
    }
    if (wantSem) {
      unsigned u[8];
#pragma unroll
      for (int k2 = 0; k2 < 8; ++k2) {
        float s0 = semb[(size_t)(2*k2  )*NPIX + p];
        float s1 = semb[(size_t)(2*k2+1)*NPIX + p];
        unsigned q0 = (unsigned)(clip01(s0)*SEMSCALE + 0.5f);
        unsigned q1 = (unsigned)(clip01(s1)*SEMSCALE + 0.5f);
        u[k2] = q0 | (q1 << 16);
      }
      ux4* dst = (ux4*)(semT + ((size_t)b*NPIX + p)*16);
      ux4 v0 = {u[0], u[1], u[2], u[3]};
      ux4 v1 = {u[4], u[5], u[6], u[7]};
      __builtin_nontemporal_store(v0, dst);
      __builtin_nontemporal_store(v1, dst + 1);
    }
  }
  __syncthreads();
  for (int i = tid; i < NBIN; i += 256) {
    unsigned v = hist[i];
    if (v) atomicAdd(&counts[b*NBIN + i], v);
  }
}

// ---------------------------------------------------------------- scatter (local scan of counts; block (0,0) publishes offs)
__global__ __launch_bounds__(256) void k_scatter(const float* __restrict__ obs,
                                                 const float* __restrict__ eve,
                                                 const unsigned* __restrict__ counts,
                                                 unsigned* __restrict__ curs,
                                                 unsigned* __restrict__ offs_g,
                                                 unsigned* __restrict__ list) {
  __shared__ unsigned hist[NBIN];
  __shared__ unsigned lbase[NBIN];
  __shared__ unsigned slot[NBIN];
  __shared__ unsigned offsL[NBINT];
  __shared__ unsigned partial[256];
  int tid = threadIdx.x;
  int b   = blockIdx.y;
  for (int i = tid; i < NBIN; i += 256) { hist[i] = 0u; slot[i] = 0u; }
  {
    unsigned loc[8]; unsigned s = 0;
#pragma unroll
    for (int k = 0; k < 8; ++k) {
      int idx = tid*8 + k;
      unsigned v = (idx < NBINT) ? counts[idx] : 0u;
      loc[k] = s; s += v;
    }
    partial[tid] = s;
    __syncthreads();
    for (int off = 1; off < 256; off <<= 1) {
      unsigned v = (tid >= off) ? partial[tid - off] : 0u;
      __syncthreads();
      partial[tid] += v;
      __syncthreads();
    }
    unsigned base = (tid > 0) ? partial[tid-1] : 0u;
#pragma unroll
    for (int k = 0; k < 8; ++k) {
      int idx = tid*8 + k;
      if (idx < NBINT) offsL[idx] = base + loc[k];
    }
    __syncthreads();
  }
  if (blockIdx.x == 0 && b == 0)
    for (int i = tid; i < NBINT; i += 256) offs_g[i] = offsL[i];

  float a  = eve[b] * D2R;
  float ca = cosf(a), sa = sinf(a);
  const float* __restrict__ dpl = obs + ((size_t)b*NCH + 3)*NPIX;
  int base = blockIdx.x * 2048;
#pragma unroll
  for (int k = 0; k < 8; ++k) {
    int p = base + k*256 + tid;
    Geo g = geom(p, dpl[p], ca, sa);
    int bins[4];
    int n = pixel_bins(g, bins);
    for (int t = 0; t < n; ++t) atomicAdd(&hist[bins[t]], 1u);
  }
  __syncthreads();
  for (int i = tid; i < NBIN; i += 256) {
    unsigned h = hist[i];
    lbase[i] = h ? (offsL[b*NBIN + i] + atomicAdd(&curs[b*NBIN + i], h)) : 0u;
  }
  __syncthreads();
#pragma unroll
  for (int k = 0; k < 8; ++k) {
    int p = base + k*256 + tid;
    Geo g = geom(p, dpl[p], ca, sa);
    int bins[4];
    int n = pixel_bins(g, bins);
    for (int t = 0; t < n; ++t) {
      int bn = bins[t];
      unsigned sidx = atomicAdd(&slot[bn], 1u);
      list[lbase[bn] + sidx] = (unsigned)p;
    }
  }
}

// ---------------------------------------------------------------- fused splat+reduce (blocks [0,2000)) + fast stream (blocks >=2000)
__global__ __launch_bounds__(512, 8) void k_splat_fast(const float* __restrict__ obs,
                                                       const unsigned short* __restrict__ semT,
                                                       const float* __restrict__ eve,
                                                       const unsigned* __restrict__ offs,
                                                       const unsigned* __restrict__ counts,
                                                       const unsigned* __restrict__ list,
                                                       float* __restrict__ av,
                                                       float* __restrict__ avs,
                                                       const float* __restrict__ maps_last,
                                                       float* __restrict__ out0,
                                                       float* __restrict__ out1,
                                                       float* __restrict__ out2,
                                                       int nSplat, int nFast) {
  __shared__ unsigned           lds0[CELLS * C0STRIDE];
  __shared__ unsigned long long ldss[CELLS * SEMSTRIDE];
  const int bid = blockIdx.x;
  const int tid = threadIdx.x;

  if (bid >= nSplat) {
    const size_t n4 = SEG/4;
    const size_t stride = (size_t)nFast * 512;
    const fx4* __restrict__ m4 = (const fx4*)maps_last;
    fx4 z4 = {0.0f, 0.0f, 0.0f, 0.0f};
    for (size_t i = (size_t)(bid - nSplat) * 512 + tid; i < n4; i += stride) {
      fx4 m = __builtin_nontemporal_load(m4 + i);
      fx4 r;
      r.x = fmaxf(m.x, 0.0f); r.y = fmaxf(m.y, 0.0f);
      r.z = fmaxf(m.z, 0.0f); r.w = fmaxf(m.w, 0.0f);
      __builtin_nontemporal_store(z4, (fx4*)out0 + i);
      __builtin_nontemporal_store(r,  (fx4*)out1 + i);
      __builtin_nontemporal_store(r,  (fx4*)out2 + i);
    }
    return;
  }

  const int reg = bid % NBIN;
  const int b   = bid / NBIN;
  const int rx0 = (reg % NRX) * TX;
  const int ry0 = (reg / NRX) * TY;

  for (int i = tid; i < CELLS * C0STRIDE; i += 512) lds0[i] = 0u;
  for (int i = tid; i < CELLS * SEMSTRIDE; i += 512) ldss[i] = 0ull;
  __syncthreads();

  float aa = eve[b] * D2R;
  float ca = cosf(aa), sa = sinf(aa);
  const float* __restrict__ dpl = obs + ((size_t)b*NCH + 3)*NPIX;

  const unsigned bin   = (unsigned)b*NBIN + reg;
  const unsigned start = offs[bin];
  const unsigned n     = counts[bin];

  for (unsigned ii0 = tid; ii0 < n; ii0 += 2048u) {
    int pid[4];
#pragma unroll
    for (int q = 0; q < 4; ++q) {
      unsigned ii = ii0 + (unsigned)q*512u;
      pid[q] = (ii < n) ? (int)list[start + ii] : -1;
    }
    float dep[4];
#pragma unroll
    for (int q = 0; q < 4; ++q)
      dep[q] = (pid[q] >= 0) ? dpl[pid[q]] : 0.0f;
#pragma unroll
    for (int q = 0; q < 4; ++q) {
      if (pid[q] < 0) continue;
      const int p = pid[q];
      Geo g = geom(p, dep[q], ca, sa);
      float px = g.px, py = g.py, pz = g.pz;
      float fx = floorf(px), fy = floorf(py), fz = floorf(pz);

      float wxa[2], wya[2], wza[2];
      int   ixa[2], iya[2], iza[2];
      bool  vx[2], vy[2], vz[2];
#pragma unroll
      for (int k = 0; k < 2; ++k) {
        float pv = fx + (float)k;
        bool sg = (pv > 0.0f) && (pv < 100.0f);
        wxa[k] = sg ? (1.0f - fabsf(px - pv)) : 0.0f;
        ixa[k] = (int)pv;
        vx[k]  = sg && (ixa[k] >= rx0) && (ixa[k] < rx0 + TX);

        pv = fy + (float)k;
        sg = (pv > 0.0f) && (pv < 100.0f);
        wya[k] = sg ? (1.0f - fabsf(py - pv)) : 0.0f;
        iya[k] = (int)pv;
        vy[k]  = sg && (iya[k] >= ry0) && (iya[k] < ry0 + TY);

        pv = fz + (float)k;
        sg = (pv > 0.0f) && (pv < 48.0f);
        wza[k] = sg ? (1.0f - fabsf(pz - pv)) : 0.0f;
        iza[k] = (int)pv;
        vz[k]  = sg;
      }

      bool needSem = false;
#pragma unroll
      for (int k = 0; k < 2; ++k)
        if (vz[k] && iza[k] >= 13 && iza[k] < 35 && wza[k] != 0.0f) needSem = true;

      float sem[16];
      if (needSem) {
        const ux4* sp = (const ux4*)(semT + ((size_t)b*NPIX + p)*16);
        ux4 a4 = sp[0], b4 = sp[1];
        sem[0]  = (float)(a4.x & 0xffffu); sem[1]  = (float)(a4.x >> 16);
        sem[2]  = (float)(a4.y & 0xffffu); sem[3]  = (float)(a4.y >> 16);
        sem[4]  = (float)(a4.z & 0xffffu); sem[5]  = (float)(a4.z >> 16);
        sem[6]  = (float)(a4.w & 0xffffu); sem[7]  = (float)(a4.w >> 16);
        sem[8]  = (float)(b4.x & 0xffffu); sem[9]  = (float)(b4.x >> 16);
        sem[10] = (float)(b4.y & 0xffffu); sem[11] = (float)(b4.y >> 16);
        sem[12] = (float)(b4.z & 0xffffu); sem[13] = (float)(b4.z >> 16);
        sem[14] = (float)(b4.w & 0xffffu); sem[15] = (float)(b4.w >> 16);
      }

#pragma unroll
      for (int cx = 0; cx < 2; ++cx) {
        if (!vx[cx] || wxa[cx] == 0.0f) continue;
#pragma unroll
        for (int cy = 0; cy < 2; ++cy) {
          if (!vy[cy]) continue;
          float wxy = wxa[cx] * wya[cy];
          if (wxy == 0.0f) continue;
          const int cell = (ixa[cx]-rx0)*TY + (iya[cy]-ry0);
#pragma unroll
          for (int cz = 0; cz < 2; ++cz) {
            if (!vz[cz]) continue;
            float wv = wxy * wza[cz];
            if (wv == 0.0f) continue;
            int zv = iza[cz];
            atomicAdd(lds0 + cell*C0STRIDE + zv, (unsigned)(wv*FPSCALE + 0.5f));  // ch0, scale 2^16
            if (zv >= 13 && zv < 35) {
              unsigned long long* p2 = ldss + (size_t)cell*SEMSTRIDE + (zv - 13)*8;
#pragma unroll
              for (int c4 = 0; c4 < 8; ++c4) {
                unsigned lo = (unsigned)(wv*sem[2*c4]   + 0.5f);   // sem already x65535
                unsigned hi = (unsigned)(wv*sem[2*c4+1] + 0.5f);
                atomicAdd(p2 + c4, ((unsigned long long)hi << 32) | (unsigned long long)lo);
              }
            }
          }
        }
      }
    }
  }
  __syncthreads();

  for (int it = tid; it < CELLS * 17; it += 512) {
    int cell = it % CELLS;
    int ch   = it / CELLS;
    int lx = cell / TY, ly = cell % TY;
    int x = rx0 + lx, y = ry0 + ly;
    if (y >= 100) continue;
    size_t pxo = (size_t)y*VR + x;
    size_t ab  = (size_t)b*18*10000;
    if (ch == 0) {
      const unsigned* cellp = lds0 + (size_t)cell * C0STRIDE;
      float all0 = 0.0f, ahp0 = 0.0f, asp0 = 0.0f;
#pragma unroll
      for (int z = 0; z < 48; ++z) {
        float v = rintf((float)cellp[z] * FPINV);
        all0 += v;
        if (z >= 13 && z < 35) ahp0 += v;
        if (z >= 20 && z < 25) asp0 += v;
      }
      av[ab + 0*10000 + pxo] = clip01(ahp0);
      av[ab + 1*10000 + pxo] = clip01(all0);
      avs[(size_t)b*10000 + pxo] = clip01(asp0);
    } else {
      int c = ch - 1;
      const unsigned* sp = (const unsigned*)(ldss + (size_t)cell * SEMSTRIDE);
      float acc = 0.0f;
      for (int z = 0; z < 22; ++z)
        acc += rintf((float)sp[(z*8 + (c >> 1))*2 + (c & 1)] * SEMINV);
      av[ab + (size_t)(2 + c)*10000 + pxo] = clip01(acc / 5.0f);
    }
  }
}

// ---------------------------------------------------------------- standalone fast path (fallback when semT/list alias out segments)
__global__ __launch_bounds__(256) void k_fast(const float* __restrict__ maps_last,
                                              float* __restrict__ out0,
                                              float* __restrict__ out1,
                                              float* __restrict__ out2) {
  const size_t n4 = SEG/4;
  const size_t stride = (size_t)gridDim.x * 256;
  const fx4* __restrict__ m4 = (const fx4*)maps_last;
  fx4 z4 = {0.0f, 0.0f, 0.0f, 0.0f};
  for (size_t i = (size_t)blockIdx.x * 256 + threadIdx.x; i < n4; i += stride) {
    fx4 m = __builtin_nontemporal_load(m4 + i);
    fx4 r;
    r.x = fmaxf(m.x, 0.0f); r.y = fmaxf(m.y, 0.0f);
    r.z = fmaxf(m.z, 0.0f); r.w = fmaxf(m.w, 0.0f);
    __builtin_nontemporal_store(z4, (fx4*)out0 + i);
    __builtin_nontemporal_store(r,  (fx4*)out1 + i);
    __builtin_nontemporal_store(r,  (fx4*)out2 + i);
  }
}

// ---------------------------------------------------------------- heavy path: fused rot+trans+maxpool+merge on window
struct Nb { float wt, w00, w10, w01, w11; int o00, o10, o01, o11; };

__device__ __forceinline__ Nb rot_taps(int xi, int yi, float ct, float st, float wt) {
  Nb nb; nb.wt = 0.0f;
  nb.w00 = nb.w10 = nb.w01 = nb.w11 = 0.0f;
  nb.o00 = nb.o10 = nb.o01 = nb.o11 = 0;
  if (xi < 0 || xi >= MSZ || yi < 0 || yi >= MSZ) return nb;
  float gx = ((xi + 0.5f)*2.0f)/480.0f - 1.0f;
  float gy = ((yi + 0.5f)*2.0f)/480.0f - 1.0f;
  float u = gx*ct - gy*st;
  float v = gx*st + gy*ct;
  float xf = (u + 1.0f)*0.5f*479.0f;
  float yf = (v + 1.0f)*0.5f*479.0f;
  float x0f = floorf(xf), y0f = floorf(yf);
  int x0 = (int)x0f, y0 = (int)y0f;
  if (x0 < 189 || x0 > 289 || y0 < 239 || y0 > 339) return nb;
  float wx = xf - x0f, wy = yf - y0f;
  bool vx0 = (x0   >= 190) && (x0   < 290);
  bool vx1 = (x0+1 >= 190) && (x0+1 < 290);
  bool vy0 = (y0   >= 240) && (y0   < 340);
  bool vy1 = (y0+1 >= 240) && (y0+1 < 340);
  int base = (y0-240)*100 + (x0-190);
  bool v00 = vx0&&vy0, v10 = vx1&&vy0, v01 = vx0&&vy1, v11 = vx1&&vy1;
  nb.w00 = v00 ? (1.0f-wx)*(1.0f-wy) : 0.0f;  nb.o00 = v00 ? base       : 0;
  nb.w10 = v10 ? wx*(1.0f-wy)        : 0.0f;  nb.o10 = v10 ? base + 1   : 0;
  nb.w01 = v01 ? (1.0f-wx)*wy        : 0.0f;  nb.o01 = v01 ? base + 100 : 0;
  nb.w11 = v11 ? wx*wy               : 0.0f;  nb.o11 = v11 ? base + 101 : 0;
  nb.wt  = wt;
  return nb;
}

__device__ __forceinline__ bool trans_nbs(int w, int h, float sx, float sy,
                                          float ct, float st, Nb nb[4]) {
#pragma unroll
  for (int i = 0; i < 4; ++i) {
    nb[i].wt = 0.0f;
    nb[i].w00 = nb[i].w10 = nb[i].w01 = nb[i].w11 = 0.0f;
    nb[i].o00 = nb[i].o10 = nb[i].o01 = nb[i].o11 = 0;
  }
  float gx = ((w + 0.5f)*2.0f)/480.0f - 1.0f;
  float gy = ((h + 0.5f)*2.0f)/480.0f - 1.0f;
  float xf = ((gx + sx) + 1.0f)*0.5f*479.0f;
  float yf = ((gy + sy) + 1.0f)*0.5f*479.0f;
  float x0f = floorf(xf), y0f = floorf(yf);
  int x0 = (int)x0f, y0 = (int)y0f;
  if (x0 < -1 || x0 > 479 || y0 < -1 || y0 > 479) return false;
  float wx = xf - x0f, wy = yf - y0f;
  nb[0] = rot_taps(x0,   y0,   ct, st, (1.0f-wx)*(1.0f-wy));
  nb[1] = rot_taps(x0+1, y0,   ct, st, wx*(1.0f-wy));
  nb[2] = rot_taps(x0,   y0+1, ct, st, (1.0f-wx)*wy);
  nb[3] = rot_taps(x0+1, y0+1, ct, st, wx*wy);
  return (nb[0].wt!=0.0f)||(nb[1].wt!=0.0f)||(nb[2].wt!=0.0f)||(nb[3].wt!=0.0f);
}

__device__ __forceinline__ float eval_plane(const float* __restrict__ plane, const Nb nb[4]) {
  float t = 0.0f;
#pragma unroll
  for (int i = 0; i < 4; ++i) {
    if (nb[i].wt == 0.0f) continue;
    float r = plane[nb[i].o00]*nb[i].w00 + plane[nb[i].o10]*nb[i].w10
            + plane[nb[i].o01]*nb[i].w01 + plane[nb[i].o11]*nb[i].w11;
    t += nb[i].wt * r;
  }
  return t;
}

#define TILE 16
__global__ __launch_bounds__(256) void k_heavy(const float* __restrict__ av,
                                               const float* __restrict__ avs,
                                               const float* __restrict__ pose_obs,
                                               const float* __restrict__ poses_last,
                                               const float* __restrict__ eve,
                                               const float* __restrict__ maps_last,
                                               float* __restrict__ out0,
                                               float* __restrict__ out1,
                                               float* __restrict__ out2) {
  __shared__ float t0s[18][19];
  const int b = blockIdx.y;

  float nx, ny, nt;
  pose_calc(pose_obs, poses_last, b, nx, ny, nt);
  float t2 = (90.0f - nt) * D2R;
  const float ct = cosf(t2), st = sinf(t2);
  const float sx = (240.0f - nx*100.0f/5.0f) / 240.0f;
  const float sy = (240.0f - ny*100.0f/5.0f) / 240.0f;
  const bool eve0 = (eve[b] == 0.0f);
  int wx0, wy0;
  {
    const float u_lo = 189.0f/239.5f - 1.0f, u_hi = 290.0f/239.5f - 1.0f;
    const float v_lo = 239.0f/239.5f - 1.0f, v_hi = 340.0f/239.5f - 1.0f;
    float ximin = 1e9f, yimin = 1e9f;
#pragma unroll
    for (int k = 0; k < 4; ++k) {
      float uu = (k & 1) ? u_hi : u_lo;
      float vv = (k & 2) ? v_hi : v_lo;
      float gxc =  uu*ct + vv*st;
      float gyc = -uu*st + vv*ct;
      float xi = (gxc + 1.0f)*240.0f - 0.5f;
      float yi = (gyc + 1.0f)*240.0f - 0.5f;
      ximin = fminf(ximin, xi);
      yimin = fminf(yimin, yi);
    }
    float wmin = 240.0f*((ximin - 1.0f)/239.5f - sx) - 0.5f;
    float hmin = 240.0f*((yimin - 1.0f)/239.5f - sy) - 0.5f;
    wx0 = min(max((int)floorf(wmin) - 3, 0), MSZ - WND);
    wy0 = min(max((int)floorf(hmin) - 3, 0), MSZ - WND);
  }
  int sxi = 0, syi = 0;
  if (b == 0) {
    float nx0, ny0, nt0;
    pose_calc(pose_obs, poses_last, 0, nx0, ny0, nt0);
    sxi = min(max((int)(nx0 * 100.0f / 5.0f), 30), 449);
    syi = min(max((int)(ny0 * 100.0f / 5.0f), 30), 449);
  }

  const int tx0 = wx0 + (blockIdx.x % NT) * TILE;
  const int ty0 = wy0 + (blockIdx.x / NT) * TILE;
  const int lx  = threadIdx.x % TILE;
  const int ly  = threadIdx.x / TILE;
  const float* __restrict__ av0 = av + (size_t)b*18*10000;

  for (int q = threadIdx.x; q < 18*18; q += 256) {
    int hy = q / 18, hx = q % 18;
    int h = ty0 + hy - 1, w = tx0 + hx - 1;
    float v;
    if (h < 0 || h >= MSZ || w < 0 || w >= MSZ) {
      v = -INFINITY;
    } else {
      Nb nb[4];
      v = trans_nbs(w, h, sx, sy, ct, st, nb) ? eval_plane(av0, nb) : 0.0f;
    }
    t0s[hy][hx] = v;
  }
  __syncthreads();

  const int h = ty0 + ly, w = tx0 + lx;
  const size_t pix = (size_t)h*MSZ + w;

  float mp = -INFINITY;
#pragma unroll
  for (int dy = 0; dy < 3; ++dy)
#pragma unroll
    for (int dx = 0; dx < 3; ++dx)
      mp = fmaxf(mp, t0s[ly+dy][lx+dx]);
  float t0 = t0s[ly+1][lx+1];

  Nb nb[4];
  bool hit = trans_nbs(w, h, sx, sy, ct, st, nb);

  float t[19];
  t[0] = t0;
  if (hit) {
#pragma unroll
    for (int s = 1; s < 18; ++s) t[s] = eval_plane(av0 + (size_t)s*10000, nb);
    t[18] = eval_plane(avs + (size_t)b*10000, nb);
  } else {
#pragma unroll
    for (int s = 1; s < 19; ++s) t[s] = 0.0f;
  }

  float t1v = t[1];
  bool kill = ((t1v - mp) > 0.8f) && eve0;

  float sg = 1.0f;
  if (b == 0) {
    int di = h - (syi - 30);
    int dj = w - (sxi - 30);
    if (di >= 0 && di < 60 && dj >= 0 && dj < 60) {
      float aa = (float)di - 29.5f;
      float bb = (float)dj - 29.5f;
      sg = (aa*aa + bb*bb <= 900.0f) ? 1.0f : 0.0f;
    } else {
      sg = 0.0f;
    }
  }
  float tsv0 = t[18] * sg;
  float ts1  = t1v * sg;
  bool kill_s = ((ts1 - tsv0) > 0.8f) && eve0;

  const float* ML = maps_last + (size_t)b*NCH*MPX;
  float* O0 = out0 + (size_t)b*NCH*MPX;
  float* O1 = out1 + (size_t)b*NCH*MPX;
  float* O2 = out2 + (size_t)b*NCH*MPX;

#pragma unroll
  for (int c = 0; c < NCH; ++c) {
    float tv  = (c == 0) ? t0 : ((c == 1) ? t1v : ((c < 4) ? 0.0f : t[c - 2]));
    float tsv = (c == 0) ? tsv0 : ((c == 1) ? ts1 : tv);
    float ml  = ML[(size_t)c*MPX + pix];
    float mpv = fmaxf(ml, tv);
    float msv = fmaxf(ml, tsv);
    if (c == 0) {
      if (kill)   mpv = 0.0f;
      if (kill_s) msv = 0.0f;
    }
    O0[(size_t)c*MPX + pix] = tv;
    O1[(size_t)c*MPX + pix] = mpv;
    O2[(size_t)c*MPX + pix] = msv;
  }
}

// ---------------------------------------------------------------- launch
extern "C" void kernel_launch(void* const* d_in, const int* in_sizes, int n_in,
                              void* d_out, int out_size, void* d_ws, size_t ws_size,
                              hipStream_t stream) {
  (void)in_sizes; (void)n_in; (void)out_size;
  const float* obs        = (const float*)d_in[0];
  const float* pose_obs   = (const float*)d_in[1];
  const float* maps_last  = (const float*)d_in[2];
  const float* poses_last = (const float*)d_in[3];
  const float* eve        = (const float*)d_in[4];
  float* out = (float*)d_out;
  float* ws  = (float*)d_ws;

  float*    av     = ws + OFF_AV;
  float*    avs    = ws + OFF_AVS;
  unsigned* counts = (unsigned*)(ws + OFF_COUNTS);
  unsigned* curs   = (unsigned*)(ws + OFF_CURS);
  unsigned* offs   = (unsigned*)(ws + OFF_OFFS);

  float* out0 = out;
  float* out1 = out + SEG;
  float* out2 = out + 2*SEG;
  float* outp = out + 3*SEG;

  const bool big_ws = (ws_size >= WS_NEED_B);
  unsigned short* semT = big_ws ? (unsigned short*)(ws + OFF_SEMT)
                                : (unsigned short*)out0;
  unsigned*       list = big_ws ? (unsigned*)(ws + OFF_LIST)
                                : (unsigned*)(out + LIST_OFF_OUT);

  k_zero<<<(2*NBINT + 255)/256, 256, 0, stream>>>(counts);
  {
    dim3 g(NPIX/2048, BS);
    k_prep<<<g, 256, 0, stream>>>(obs, pose_obs, poses_last, eve, counts, semT, outp);
    k_scatter<<<g, 256, 0, stream>>>(obs, eve, counts, curs, offs, list);
  }
  {
    const int nSplat = NBINT;                // 2000 static bins
    const int nFast  = big_ws ? 1024 : 0;    // overlap fast stream with splat phase
    k_splat_fast<<<nSplat + nFast, 512, 0, stream>>>(obs, semT, eve, offs, counts, list,
                                                     av, avs, maps_last, out0, out1, out2,
                                                     nSplat, nFast);
  }
  if (!big_ws) {
    k_fast<<<2048, 256, 0, stream>>>(maps_last, out0, out1, out2);
  }
  {
    dim3 g(NT*NT, BS);
    k_heavy<<<g, 256, 0, stream>>>(av, avs, pose_obs, poses_last, eve, maps_last, out0, out1, out2);
  }
}

// Round 18
// 200.592 us; speedup vs baseline: 1.0632x; 1.0632x over previous
//
#include <hip/hip_runtime.h>
#include <math.h>

#define BS 4
#define NCH 20
#define IMH 480
#define IMW 640
#define NPIX (IMH*IMW)           /* 307200 */
#define MSZ 480
#define MPX (MSZ*MSZ)            /* 230400 */
#define VR 100

#define TX 5
#define TY 8
#define NRX 20
#define NRY 13
#define NBIN (NRX*NRY)           /* 260 */
#define NBINT (BS*NBIN)          /* 1040 */
#define CELLS (TX*TY)            /* 40 */
#define C0STRIDE 49              /* u32 stride, odd -> bank spread */
#define SEMSTRIDE 177            /* u64 stride, mod 16 == 1 -> bank-pair spread (22*8=176 used) */
/* LDS: 40*49*4 + 40*177*8 = 7840 + 56640 = 64480 B -> 2 blocks/CU */

#define WND 176                  /* heavy-pass window (>= 152 worst-case) */
#define NT  11                   /* WND/16 */

#define FPSCALE 65536.0f
#define FPINV   (1.0f/65536.0f)
#define SEMSCALE 65535.0f
#define SEMINV   (1.0f/65535.0f)

#define FCONST 388.19028f        /* 320 / tan(39.5 deg) */
#define D2R    0.017453292519943295f
#define R2DF   57.29577951308232f

typedef float    fx4  __attribute__((ext_vector_type(4)));
typedef unsigned ux4  __attribute__((ext_vector_type(4)));

static constexpr size_t SEG = (size_t)BS*NCH*MPX;            // 18,432,000 floats per output map
static constexpr size_t SEMT_FLOATS = (size_t)BS*NPIX*8;     // u16 semT = 9,830,400 float-equivalents
static constexpr size_t LIST_CAP    = (size_t)4*BS*NPIX;     // 4,915,200 entries (exact worst case)
// out-segment fallback layout:
static constexpr size_t LIST_OFF_OUT = SEMT_FLOATS;
static_assert(LIST_OFF_OUT + LIST_CAP < 2*SEG, "semT+list must fit in out0+out1 segments");

// ws layout (float offsets)
static constexpr size_t OFF_AV     = 0;            // BS*18*10000
static constexpr size_t OFF_AVS    = 720000;       // BS*10000
static constexpr size_t OFF_COUNTS = 1681664;      // 1040 uints
static constexpr size_t OFF_CURS   = 1682704;      // 1040 uints (contiguous with counts)
static constexpr size_t OFF_OFFS   = 1683760;      // 1040 uints
static constexpr size_t OFF_SEMT   = 1684800;      // 16B-aligned; semT (ws path)
static constexpr size_t OFF_LIST   = OFF_SEMT + SEMT_FLOATS;   // 11,515,200
static constexpr size_t WS_NEED_B  = (OFF_LIST + LIST_CAP) * 4;  // ~65.7 MB
static_assert(OFF_CURS == OFF_COUNTS + NBINT, "counts/curs must be contiguous for k_zero");

__device__ __forceinline__ float clip01(float v) { return fminf(fmaxf(v, 0.0f), 1.0f); }

struct Geo { float px, py, pz; };

__device__ __forceinline__ Geo geom(int p, float depth, float ca, float sa) {
  int j = p % IMW;
  int i = p / IMW;
  float dF = depth * (1.0f / FCONST);
  float X  = ((float)j - 319.5f) * dF;
  X += 250.0f;
  float gz = (float)(IMH - 1 - i);
  float Zc = (gz - 239.5f) * dF;
  float Y  = ca*depth - sa*Zc;
  float Z  = sa*depth + ca*Zc + 88.0f;
  float xs = (X/5.0f - 50.0f)/100.0f*2.0f;
  float ys = (Y/5.0f - 50.0f)/100.0f*2.0f;
  float zs = (Z/5.0f - 16.0f)/48.0f*2.0f;
  Geo g;
  g.px = xs*50.0f + 50.0f;
  g.py = ys*50.0f + 50.0f;
  g.pz = zs*24.0f + 24.0f;
  return g;
}

__device__ __forceinline__ int pixel_bins(Geo g, int bins[4]) {
  float fx = floorf(g.px), fy = floorf(g.py), fz = floorf(g.pz);
  float fx1 = fx + 1.0f, fy1 = fy + 1.0f, fz1 = fz + 1.0f;
  bool vx0 = (fx  > 0.0f) && (fx  < 100.0f);
  bool vx1 = (fx1 > 0.0f) && (fx1 < 100.0f);
  bool vy0 = (fy  > 0.0f) && (fy  < 100.0f);
  bool vy1 = (fy1 > 0.0f) && (fy1 < 100.0f);
  bool vz0 = (fz  > 0.0f) && (fz  < 48.0f);
  bool vz1 = (fz1 > 0.0f) && (fz1 < 48.0f);
  if (!((vx0||vx1) && (vy0||vy1) && (vz0||vz1))) return 0;
  int rxs[2]; int nx = 0;
  if (vx0) rxs[nx++] = (int)fx / TX;
  if (vx1) { int r = (int)fx1 / TX; if (!nx || r != rxs[0]) rxs[nx++] = r; }
  int rys[2]; int ny = 0;
  if (vy0) rys[ny++] = (int)fy / TY;
  if (vy1) { int r = (int)fy1 / TY; if (!ny || r != rys[0]) rys[ny++] = r; }
  int n = 0;
  for (int a = 0; a < ny; ++a)
    for (int c = 0; c < nx; ++c)
      bins[n++] = rys[a]*NRX + rxs[c];
  return n;
}

__device__ __forceinline__ void pose_calc(const float* __restrict__ pose_obs,
                                          const float* __restrict__ poses_last,
                                          int b, float& nx, float& ny, float& nt) {
  float pl0 = poses_last[b*3+0], pl1 = poses_last[b*3+1], pl2 = poses_last[b*3+2];
  float po0 = pose_obs[b*3+0],   po1 = pose_obs[b*3+1],   po2 = pose_obs[b*3+2];
  float r  = pl2 / R2DF;
  float sr = sinf(r), cr = cosf(r);
  ny = pl1 + po0*sr + po1*cr;
  nx = pl0 + po0*cr - po1*sr;
  nt = pl2 + po2*R2DF;
  nt = fmodf(nt - 180.0f, 360.0f) + 180.0f;
  nt = fmodf(nt + 180.0f, 360.0f) - 180.0f;
}

// ---------------------------------------------------------------- zero counts+curs (contiguous 2*NBINT words)
__global__ __launch_bounds__(256) void k_zero(unsigned* __restrict__ counts_curs) {
  int i = blockIdx.x * 256 + threadIdx.x;
  if (i < 2*NBINT) counts_curs[i] = 0u;
}

// ---------------------------------------------------------------- prep: bin count + predicated u16 sem transpose (+ poses output)
__global__ __launch_bounds__(256) void k_prep(const float* __restrict__ obs,
                                              const float* __restrict__ pose_obs,
                                              const float* __restrict__ poses_last,
                                              const float* __restrict__ eve,
                                              unsigned* __restrict__ counts,
                                              unsigned short* __restrict__ semT,
                                              float* __restrict__ out_poses) {
  __shared__ unsigned hist[NBIN];
  int tid = threadIdx.x;
  int b   = blockIdx.y;
  if (blockIdx.x == 0 && b == 0 && tid < BS) {
    float nx, ny, nt;
    pose_calc(pose_obs, poses_last, tid, nx, ny, nt);
    out_poses[tid*3+0] = nx;
    out_poses[tid*3+1] = ny;
    out_poses[tid*3+2] = nt;
  }
  for (int i = tid; i < NBIN; i += 256) hist[i] = 0u;
  __syncthreads();
  float a  = eve[b] * D2R;
  float ca = cosf(a), sa = sinf(a);
  const float* __restrict__ dpl  = obs + ((size_t)b*NCH + 3)*NPIX;
  const float* __restrict__ semb = obs + ((size_t)b*NCH + 4)*NPIX;
  int base = blockIdx.x * 2048;
#pragma unroll
  for (int k = 0; k < 8; ++k) {
    int p = base + k*256 + tid;
    Geo g = geom(p, dpl[p], ca, sa);
    int bins[4];
    int n = pixel_bins(g, bins);
    for (int t = 0; t < n; ++t) atomicAdd(&hist[bins[t]], 1u);
    bool wantSem = false;
    if (n > 0) {
      float fz = floorf(g.pz);
#pragma unroll
      for (int kk = 0; kk < 2; ++kk) {
        float pv = fz + (float)kk;
        if (pv > 0.0f && pv < 48.0f) {
          int zv = (int)pv;
          if (zv >= 13 && zv < 35) wantSem = true;
        }
      }
    }
    if (wantSem) {
      unsigned u[8];
#pragma unroll
      for (int k2 = 0; k2 < 8; ++k2) {
        float s0 = semb[(size_t)(2*k2  )*NPIX + p];
        float s1 = semb[(size_t)(2*k2+1)*NPIX + p];
        unsigned q0 = (unsigned)(clip01(s0)*SEMSCALE + 0.5f);
        unsigned q1 = (unsigned)(clip01(s1)*SEMSCALE + 0.5f);
        u[k2] = q0 | (q1 << 16);
      }
      ux4* dst = (ux4*)(semT + ((size_t)b*NPIX + p)*16);
      ux4 v0 = {u[0], u[1], u[2], u[3]};
      ux4 v1 = {u[4], u[5], u[6], u[7]};
      __builtin_nontemporal_store(v0, dst);
      __builtin_nontemporal_store(v1, dst + 1);
    }
  }
  __syncthreads();
  for (int i = tid; i < NBIN; i += 256) {
    unsigned v = hist[i];
    if (v) atomicAdd(&counts[b*NBIN + i], v);
  }
}

// ---------------------------------------------------------------- scatter (local scan of counts; block (0,0) publishes offs)
__global__ __launch_bounds__(256) void k_scatter(const float* __restrict__ obs,
                                                 const float* __restrict__ eve,
                                                 const unsigned* __restrict__ counts,
                                                 unsigned* __restrict__ curs,
                                                 unsigned* __restrict__ offs_g,
                                                 unsigned* __restrict__ list) {
  __shared__ unsigned hist[NBIN];
  __shared__ unsigned lbase[NBIN];
  __shared__ unsigned slot[NBIN];
  __shared__ unsigned offsL[NBINT];
  __shared__ unsigned partial[256];
  int tid = threadIdx.x;
  int b   = blockIdx.y;
  for (int i = tid; i < NBIN; i += 256) { hist[i] = 0u; slot[i] = 0u; }
  {
    unsigned loc[5]; unsigned s = 0;
#pragma unroll
    for (int k = 0; k < 5; ++k) {
      int idx = tid*5 + k;
      unsigned v = (idx < NBINT) ? counts[idx] : 0u;
      loc[k] = s; s += v;
    }
    partial[tid] = s;
    __syncthreads();
    for (int off = 1; off < 256; off <<= 1) {
      unsigned v = (tid >= off) ? partial[tid - off] : 0u;
      __syncthreads();
      partial[tid] += v;
      __syncthreads();
    }
    unsigned base = (tid > 0) ? partial[tid-1] : 0u;
#pragma unroll
    for (int k = 0; k < 5; ++k) {
      int idx = tid*5 + k;
      if (idx < NBINT) offsL[idx] = base + loc[k];
    }
    __syncthreads();
  }
  if (blockIdx.x == 0 && b == 0)
    for (int i = tid; i < NBINT; i += 256) offs_g[i] = offsL[i];

  float a  = eve[b] * D2R;
  float ca = cosf(a), sa = sinf(a);
  const float* __restrict__ dpl = obs + ((size_t)b*NCH + 3)*NPIX;
  int base = blockIdx.x * 2048;
#pragma unroll
  for (int k = 0; k < 8; ++k) {
    int p = base + k*256 + tid;
    Geo g = geom(p, dpl[p], ca, sa);
    int bins[4];
    int n = pixel_bins(g, bins);
    for (int t = 0; t < n; ++t) atomicAdd(&hist[bins[t]], 1u);
  }
  __syncthreads();
  for (int i = tid; i < NBIN; i += 256) {
    unsigned h = hist[i];
    lbase[i] = h ? (offsL[b*NBIN + i] + atomicAdd(&curs[b*NBIN + i], h)) : 0u;
  }
  __syncthreads();
#pragma unroll
  for (int k = 0; k < 8; ++k) {
    int p = base + k*256 + tid;
    Geo g = geom(p, dpl[p], ca, sa);
    int bins[4];
    int n = pixel_bins(g, bins);
    for (int t = 0; t < n; ++t) {
      int bn = bins[t];
      unsigned sidx = atomicAdd(&slot[bn], 1u);
      list[lbase[bn] + sidx] = (unsigned)p;
    }
  }
}

// ---------------------------------------------------------------- fused splat+reduce (blocks [0,1040)) + fast stream (blocks >=1040)
// u64-packed sem atomics: 8 ds_add_u64 per corner instead of 16 ds_add_u32.
__global__ __launch_bounds__(1024, 8) void k_splat_fast(const float* __restrict__ obs,
                                                        const unsigned short* __restrict__ semT,
                                                        const float* __restrict__ eve,
                                                        const unsigned* __restrict__ offs,
                                                        const unsigned* __restrict__ counts,
                                                        const unsigned* __restrict__ list,
                                                        float* __restrict__ av,
                                                        float* __restrict__ avs,
                                                        const float* __restrict__ maps_last,
                                                        float* __restrict__ out0,
                                                        float* __restrict__ out1,
                                                        float* __restrict__ out2,
                                                        int nSplat, int nFast) {
  __shared__ unsigned           lds0[CELLS * C0STRIDE];
  __shared__ unsigned long long ldss[CELLS * SEMSTRIDE];
  const int bid = blockIdx.x;
  const int tid = threadIdx.x;

  if (bid >= nSplat) {
    const size_t n4 = SEG/4;
    const size_t stride = (size_t)nFast * 1024;
    const fx4* __restrict__ m4 = (const fx4*)maps_last;
    fx4 z4 = {0.0f, 0.0f, 0.0f, 0.0f};
    for (size_t i = (size_t)(bid - nSplat) * 1024 + tid; i < n4; i += stride) {
      fx4 m = __builtin_nontemporal_load(m4 + i);
      fx4 r;
      r.x = fmaxf(m.x, 0.0f); r.y = fmaxf(m.y, 0.0f);
      r.z = fmaxf(m.z, 0.0f); r.w = fmaxf(m.w, 0.0f);
      __builtin_nontemporal_store(z4, (fx4*)out0 + i);
      __builtin_nontemporal_store(r,  (fx4*)out1 + i);
      __builtin_nontemporal_store(r,  (fx4*)out2 + i);
    }
    return;
  }

  const int reg = bid % NBIN;
  const int b   = bid / NBIN;
  const int rx0 = (reg % NRX) * TX;
  const int ry0 = (reg / NRX) * TY;

  for (int i = tid; i < CELLS * C0STRIDE; i += 1024) lds0[i] = 0u;
  for (int i = tid; i < CELLS * SEMSTRIDE; i += 1024) ldss[i] = 0ull;
  __syncthreads();

  float aa = eve[b] * D2R;
  float ca = cosf(aa), sa = sinf(aa);
  const float* __restrict__ dpl = obs + ((size_t)b*NCH + 3)*NPIX;

  const unsigned bin   = (unsigned)b*NBIN + reg;
  const unsigned start = offs[bin];
  const unsigned n     = counts[bin];

  for (unsigned ii0 = tid; ii0 < n; ii0 += 4096u) {
    int pid[4];
#pragma unroll
    for (int q = 0; q < 4; ++q) {
      unsigned ii = ii0 + (unsigned)q*1024u;
      pid[q] = (ii < n) ? (int)list[start + ii] : -1;
    }
    float dep[4];
#pragma unroll
    for (int q = 0; q < 4; ++q)
      dep[q] = (pid[q] >= 0) ? dpl[pid[q]] : 0.0f;
#pragma unroll
    for (int q = 0; q < 4; ++q) {
      if (pid[q] < 0) continue;
      const int p = pid[q];
      Geo g = geom(p, dep[q], ca, sa);
      float px = g.px, py = g.py, pz = g.pz;
      float fx = floorf(px), fy = floorf(py), fz = floorf(pz);

      float wxa[2], wya[2], wza[2];
      int   ixa[2], iya[2], iza[2];
      bool  vx[2], vy[2], vz[2];
#pragma unroll
      for (int k = 0; k < 2; ++k) {
        float pv = fx + (float)k;
        bool sg = (pv > 0.0f) && (pv < 100.0f);
        wxa[k] = sg ? (1.0f - fabsf(px - pv)) : 0.0f;
        ixa[k] = (int)pv;
        vx[k]  = sg && (ixa[k] >= rx0) && (ixa[k] < rx0 + TX);

        pv = fy + (float)k;
        sg = (pv > 0.0f) && (pv < 100.0f);
        wya[k] = sg ? (1.0f - fabsf(py - pv)) : 0.0f;
        iya[k] = (int)pv;
        vy[k]  = sg && (iya[k] >= ry0) && (iya[k] < ry0 + TY);

        pv = fz + (float)k;
        sg = (pv > 0.0f) && (pv < 48.0f);
        wza[k] = sg ? (1.0f - fabsf(pz - pv)) : 0.0f;
        iza[k] = (int)pv;
        vz[k]  = sg;
      }

      bool needSem = false;
#pragma unroll
      for (int k = 0; k < 2; ++k)
        if (vz[k] && iza[k] >= 13 && iza[k] < 35 && wza[k] != 0.0f) needSem = true;

      float sem[16];
      if (needSem) {
        const ux4* sp = (const ux4*)(semT + ((size_t)b*NPIX + p)*16);
        ux4 a4 = sp[0], b4 = sp[1];
        sem[0]  = (float)(a4.x & 0xffffu); sem[1]  = (float)(a4.x >> 16);
        sem[2]  = (float)(a4.y & 0xffffu); sem[3]  = (float)(a4.y >> 16);
        sem[4]  = (float)(a4.z & 0xffffu); sem[5]  = (float)(a4.z >> 16);
        sem[6]  = (float)(a4.w & 0xffffu); sem[7]  = (float)(a4.w >> 16);
        sem[8]  = (float)(b4.x & 0xffffu); sem[9]  = (float)(b4.x >> 16);
        sem[10] = (float)(b4.y & 0xffffu); sem[11] = (float)(b4.y >> 16);
        sem[12] = (float)(b4.z & 0xffffu); sem[13] = (float)(b4.z >> 16);
        sem[14] = (float)(b4.w & 0xffffu); sem[15] = (float)(b4.w >> 16);
      }

#pragma unroll
      for (int cx = 0; cx < 2; ++cx) {
        if (!vx[cx] || wxa[cx] == 0.0f) continue;
#pragma unroll
        for (int cy = 0; cy < 2; ++cy) {
          if (!vy[cy]) continue;
          float wxy = wxa[cx] * wya[cy];
          if (wxy == 0.0f) continue;
          const int cell = (ixa[cx]-rx0)*TY + (iya[cy]-ry0);
#pragma unroll
          for (int cz = 0; cz < 2; ++cz) {
            if (!vz[cz]) continue;
            float wv = wxy * wza[cz];
            if (wv == 0.0f) continue;
            int zv = iza[cz];
            atomicAdd(lds0 + cell*C0STRIDE + zv, (unsigned)(wv*FPSCALE + 0.5f));  // ch0, scale 2^16
            if (zv >= 13 && zv < 35) {
              unsigned long long* p2 = ldss + (size_t)cell*SEMSTRIDE + (zv - 13)*8;
#pragma unroll
              for (int c4 = 0; c4 < 8; ++c4) {
                unsigned lo = (unsigned)(wv*sem[2*c4]   + 0.5f);   // sem already x65535
                unsigned hi = (unsigned)(wv*sem[2*c4+1] + 0.5f);
                atomicAdd(p2 + c4, ((unsigned long long)hi << 32) | (unsigned long long)lo);
              }
            }
          }
        }
      }
    }
  }
  __syncthreads();

  for (int it = tid; it < CELLS * 17; it += 1024) {
    int cell = it % CELLS;
    int ch   = it / CELLS;
    int lx = cell / TY, ly = cell % TY;
    int x = rx0 + lx, y = ry0 + ly;
    if (y >= 100) continue;
    size_t pxo = (size_t)y*VR + x;
    size_t ab  = (size_t)b*18*10000;
    if (ch == 0) {
      const unsigned* cellp = lds0 + (size_t)cell * C0STRIDE;
      float all0 = 0.0f, ahp0 = 0.0f, asp0 = 0.0f;
#pragma unroll
      for (int z = 0; z < 48; ++z) {
        float v = rintf((float)cellp[z] * FPINV);
        all0 += v;
        if (z >= 13 && z < 35) ahp0 += v;
        if (z >= 20 && z < 25) asp0 += v;
      }
      av[ab + 0*10000 + pxo] = clip01(ahp0);
      av[ab + 1*10000 + pxo] = clip01(all0);
      avs[(size_t)b*10000 + pxo] = clip01(asp0);
    } else {
      int c = ch - 1;
      const unsigned* sp = (const unsigned*)(ldss + (size_t)cell * SEMSTRIDE);
      float acc = 0.0f;
      for (int z = 0; z < 22; ++z)
        acc += rintf((float)sp[(z*8 + (c >> 1))*2 + (c & 1)] * SEMINV);
      av[ab + (size_t)(2 + c)*10000 + pxo] = clip01(acc / 5.0f);
    }
  }
}

// ---------------------------------------------------------------- standalone fast path (fallback when semT/list alias out segments)
__global__ __launch_bounds__(256) void k_fast(const float* __restrict__ maps_last,
                                              float* __restrict__ out0,
                                              float* __restrict__ out1,
                                              float* __restrict__ out2) {
  const size_t n4 = SEG/4;
  const size_t stride = (size_t)gridDim.x * 256;
  const fx4* __restrict__ m4 = (const fx4*)maps_last;
  fx4 z4 = {0.0f, 0.0f, 0.0f, 0.0f};
  for (size_t i = (size_t)blockIdx.x * 256 + threadIdx.x; i < n4; i += stride) {
    fx4 m = __builtin_nontemporal_load(m4 + i);
    fx4 r;
    r.x = fmaxf(m.x, 0.0f); r.y = fmaxf(m.y, 0.0f);
    r.z = fmaxf(m.z, 0.0f); r.w = fmaxf(m.w, 0.0f);
    __builtin_nontemporal_store(z4, (fx4*)out0 + i);
    __builtin_nontemporal_store(r,  (fx4*)out1 + i);
    __builtin_nontemporal_store(r,  (fx4*)out2 + i);
  }
}

// ---------------------------------------------------------------- heavy path: fused rot+trans+maxpool+merge on window
struct Nb { float wt, w00, w10, w01, w11; int o00, o10, o01, o11; };

__device__ __forceinline__ Nb rot_taps(int xi, int yi, float ct, float st, float wt) {
  Nb nb; nb.wt = 0.0f;
  nb.w00 = nb.w10 = nb.w01 = nb.w11 = 0.0f;
  nb.o00 = nb.o10 = nb.o01 = nb.o11 = 0;
  if (xi < 0 || xi >= MSZ || yi < 0 || yi >= MSZ) return nb;
  float gx = ((xi + 0.5f)*2.0f)/480.0f - 1.0f;
  float gy = ((yi + 0.5f)*2.0f)/480.0f - 1.0f;
  float u = gx*ct - gy*st;
  float v = gx*st + gy*ct;
  float xf = (u + 1.0f)*0.5f*479.0f;
  float yf = (v + 1.0f)*0.5f*479.0f;
  float x0f = floorf(xf), y0f = floorf(yf);
  int x0 = (int)x0f, y0 = (int)y0f;
  if (x0 < 189 || x0 > 289 || y0 < 239 || y0 > 339) return nb;
  float wx = xf - x0f, wy = yf - y0f;
  bool vx0 = (x0   >= 190) && (x0   < 290);
  bool vx1 = (x0+1 >= 190) && (x0+1 < 290);
  bool vy0 = (y0   >= 240) && (y0   < 340);
  bool vy1 = (y0+1 >= 240) && (y0+1 < 340);
  int base = (y0-240)*100 + (x0-190);
  bool v00 = vx0&&vy0, v10 = vx1&&vy0, v01 = vx0&&vy1, v11 = vx1&&vy1;
  nb.w00 = v00 ? (1.0f-wx)*(1.0f-wy) : 0.0f;  nb.o00 = v00 ? base       : 0;
  nb.w10 = v10 ? wx*(1.0f-wy)        : 0.0f;  nb.o10 = v10 ? base + 1   : 0;
  nb.w01 = v01 ? (1.0f-wx)*wy        : 0.0f;  nb.o01 = v01 ? base + 100 : 0;
  nb.w11 = v11 ? wx*wy               : 0.0f;  nb.o11 = v11 ? base + 101 : 0;
  nb.wt  = wt;
  return nb;
}

__device__ __forceinline__ bool trans_nbs(int w, int h, float sx, float sy,
                                          float ct, float st, Nb nb[4]) {
#pragma unroll
  for (int i = 0; i < 4; ++i) {
    nb[i].wt = 0.0f;
    nb[i].w00 = nb[i].w10 = nb[i].w01 = nb[i].w11 = 0.0f;
    nb[i].o00 = nb[i].o10 = nb[i].o01 = nb[i].o11 = 0;
  }
  float gx = ((w + 0.5f)*2.0f)/480.0f - 1.0f;
  float gy = ((h + 0.5f)*2.0f)/480.0f - 1.0f;
  float xf = ((gx + sx) + 1.0f)*0.5f*479.0f;
  float yf = ((gy + sy) + 1.0f)*0.5f*479.0f;
  float x0f = floorf(xf), y0f = floorf(yf);
  int x0 = (int)x0f, y0 = (int)y0f;
  if (x0 < -1 || x0 > 479 || y0 < -1 || y0 > 479) return false;
  float wx = xf - x0f, wy = yf - y0f;
  nb[0] = rot_taps(x0,   y0,   ct, st, (1.0f-wx)*(1.0f-wy));
  nb[1] = rot_taps(x0+1, y0,   ct, st, wx*(1.0f-wy));
  nb[2] = rot_taps(x0,   y0+1, ct, st, (1.0f-wx)*wy);
  nb[3] = rot_taps(x0+1, y0+1, ct, st, wx*wy);
  return (nb[0].wt!=0.0f)||(nb[1].wt!=0.0f)||(nb[2].wt!=0.0f)||(nb[3].wt!=0.0f);
}

__device__ __forceinline__ float eval_plane(const float* __restrict__ plane, const Nb nb[4]) {
  float t = 0.0f;
#pragma unroll
  for (int i = 0; i < 4; ++i) {
    if (nb[i].wt == 0.0f) continue;
    float r = plane[nb[i].o00]*nb[i].w00 + plane[nb[i].o10]*nb[i].w10
            + plane[nb[i].o01]*nb[i].w01 + plane[nb[i].o11]*nb[i].w11;
    t += nb[i].wt * r;
  }
  return t;
}

#define TILE 16
__global__ __launch_bounds__(256) void k_heavy(const float* __restrict__ av,
                                               const float* __restrict__ avs,
                                               const float* __restrict__ pose_obs,
                                               const float* __restrict__ poses_last,
                                               const float* __restrict__ eve,
                                               const float* __restrict__ maps_last,
                                               float* __restrict__ out0,
                                               float* __restrict__ out1,
                                               float* __restrict__ out2) {
  __shared__ float t0s[18][19];
  const int b = blockIdx.y;

  float nx, ny, nt;
  pose_calc(pose_obs, poses_last, b, nx, ny, nt);
  float t2 = (90.0f - nt) * D2R;
  const float ct = cosf(t2), st = sinf(t2);
  const float sx = (240.0f - nx*100.0f/5.0f) / 240.0f;
  const float sy = (240.0f - ny*100.0f/5.0f) / 240.0f;
  const bool eve0 = (eve[b] == 0.0f);
  int wx0, wy0;
  {
    const float u_lo = 189.0f/239.5f - 1.0f, u_hi = 290.0f/239.5f - 1.0f;
    const float v_lo = 239.0f/239.5f - 1.0f, v_hi = 340.0f/239.5f - 1.0f;
    float ximin = 1e9f, yimin = 1e9f;
#pragma unroll
    for (int k = 0; k < 4; ++k) {
      float uu = (k & 1) ? u_hi : u_lo;
      float vv = (k & 2) ? v_hi : v_lo;
      float gxc =  uu*ct + vv*st;
      float gyc = -uu*st + vv*ct;
      float xi = (gxc + 1.0f)*240.0f - 0.5f;
      float yi = (gyc + 1.0f)*240.0f - 0.5f;
      ximin = fminf(ximin, xi);
      yimin = fminf(yimin, yi);
    }
    float wmin = 240.0f*((ximin - 1.0f)/239.5f - sx) - 0.5f;
    float hmin = 240.0f*((yimin - 1.0f)/239.5f - sy) - 0.5f;
    wx0 = min(max((int)floorf(wmin) - 3, 0), MSZ - WND);
    wy0 = min(max((int)floorf(hmin) - 3, 0), MSZ - WND);
  }
  int sxi = 0, syi = 0;
  if (b == 0) {
    float nx0, ny0, nt0;
    pose_calc(pose_obs, poses_last, 0, nx0, ny0, nt0);
    sxi = min(max((int)(nx0 * 100.0f / 5.0f), 30), 449);
    syi = min(max((int)(ny0 * 100.0f / 5.0f), 30), 449);
  }

  const int tx0 = wx0 + (blockIdx.x % NT) * TILE;
  const int ty0 = wy0 + (blockIdx.x / NT) * TILE;
  const int lx  = threadIdx.x % TILE;
  const int ly  = threadIdx.x / TILE;
  const float* __restrict__ av0 = av + (size_t)b*18*10000;

  for (int q = threadIdx.x; q < 18*18; q += 256) {
    int hy = q / 18, hx = q % 18;
    int h = ty0 + hy - 1, w = tx0 + hx - 1;
    float v;
    if (h < 0 || h >= MSZ || w < 0 || w >= MSZ) {
      v = -INFINITY;
    } else {
      Nb nb[4];
      v = trans_nbs(w, h, sx, sy, ct, st, nb) ? eval_plane(av0, nb) : 0.0f;
    }
    t0s[hy][hx] = v;
  }
  __syncthreads();

  const int h = ty0 + ly, w = tx0 + lx;
  const size_t pix = (size_t)h*MSZ + w;

  float mp = -INFINITY;
#pragma unroll
  for (int dy = 0; dy < 3; ++dy)
#pragma unroll
    for (int dx = 0; dx < 3; ++dx)
      mp = fmaxf(mp, t0s[ly+dy][lx+dx]);
  float t0 = t0s[ly+1][lx+1];

  Nb nb[4];
  bool hit = trans_nbs(w, h, sx, sy, ct, st, nb);

  float t[19];
  t[0] = t0;
  if (hit) {
#pragma unroll
    for (int s = 1; s < 18; ++s) t[s] = eval_plane(av0 + (size_t)s*10000, nb);
    t[18] = eval_plane(avs + (size_t)b*10000, nb);
  } else {
#pragma unroll
    for (int s = 1; s < 19; ++s) t[s] = 0.0f;
  }

  float t1v = t[1];
  bool kill = ((t1v - mp) > 0.8f) && eve0;

  float sg = 1.0f;
  if (b == 0) {
    int di = h - (syi - 30);
    int dj = w - (sxi - 30);
    if (di >= 0 && di < 60 && dj >= 0 && dj < 60) {
      float aa = (float)di - 29.5f;
      float bb = (float)dj - 29.5f;
      sg = (aa*aa + bb*bb <= 900.0f) ? 1.0f : 0.0f;
    } else {
      sg = 0.0f;
    }
  }
  float tsv0 = t[18] * sg;
  float ts1  = t1v * sg;
  bool kill_s = ((ts1 - tsv0) > 0.8f) && eve0;

  const float* ML = maps_last + (size_t)b*NCH*MPX;
  float* O0 = out0 + (size_t)b*NCH*MPX;
  float* O1 = out1 + (size_t)b*NCH*MPX;
  float* O2 = out2 + (size_t)b*NCH*MPX;

#pragma unroll
  for (int c = 0; c < NCH; ++c) {
    float tv  = (c == 0) ? t0 : ((c == 1) ? t1v : ((c < 4) ? 0.0f : t[c - 2]));
    float tsv = (c == 0) ? tsv0 : ((c == 1) ? ts1 : tv);
    float ml  = ML[(size_t)c*MPX + pix];
    float mpv = fmaxf(ml, tv);
    float msv = fmaxf(ml, tsv);
    if (c == 0) {
      if (kill)   mpv = 0.0f;
      if (kill_s) msv = 0.0f;
    }
    O0[(size_t)c*MPX + pix] = tv;
    O1[(size_t)c*MPX + pix] = mpv;
    O2[(size_t)c*MPX + pix] = msv;
  }
}

// ---------------------------------------------------------------- launch
extern "C" void kernel_launch(void* const* d_in, const int* in_sizes, int n_in,
                              void* d_out, int out_size, void* d_ws, size_t ws_size,
                              hipStream_t stream) {
  (void)in_sizes; (void)n_in; (void)out_size;
  const float* obs        = (const float*)d_in[0];
  const float* pose_obs   = (const float*)d_in[1];
  const float* maps_last  = (const float*)d_in[2];
  const float* poses_last = (const float*)d_in[3];
  const float* eve        = (const float*)d_in[4];
  float* out = (float*)d_out;
  float* ws  = (float*)d_ws;

  float*    av     = ws + OFF_AV;
  float*    avs    = ws + OFF_AVS;
  unsigned* counts = (unsigned*)(ws + OFF_COUNTS);
  unsigned* curs   = (unsigned*)(ws + OFF_CURS);
  unsigned* offs   = (unsigned*)(ws + OFF_OFFS);

  float* out0 = out;
  float* out1 = out + SEG;
  float* out2 = out + 2*SEG;
  float* outp = out + 3*SEG;

  const bool big_ws = (ws_size >= WS_NEED_B);
  unsigned short* semT = big_ws ? (unsigned short*)(ws + OFF_SEMT)
                                : (unsigned short*)out0;
  unsigned*       list = big_ws ? (unsigned*)(ws + OFF_LIST)
                                : (unsigned*)(out + LIST_OFF_OUT);

  k_zero<<<(2*NBINT + 255)/256, 256, 0, stream>>>(counts);
  {
    dim3 g(NPIX/2048, BS);
    k_prep<<<g, 256, 0, stream>>>(obs, pose_obs, poses_last, eve, counts, semT, outp);
    k_scatter<<<g, 256, 0, stream>>>(obs, eve, counts, curs, offs, list);
  }
  {
    const int nSplat = NBINT;                // 1040 static bins
    const int nFast  = big_ws ? 1024 : 0;    // overlap fast stream with splat phase
    k_splat_fast<<<nSplat + nFast, 1024, 0, stream>>>(obs, semT, eve, offs, counts, list,
                                                      av, avs, maps_last, out0, out1, out2,
                                                      nSplat, nFast);
  }
  if (!big_ws) {
    k_fast<<<2048, 256, 0, stream>>>(maps_last, out0, out1, out2);
  }
  {
    dim3 g(NT*NT, BS);
    k_heavy<<<g, 256, 0, stream>>>(av, avs, pose_obs, poses_last, eve, maps_last, out0, out1, out2);
  }
}